// Round 16
// baseline (102.480 us; speedup 1.0000x reference)
//
#include <hip/hip_runtime.h>
#include <hip/hip_bf16.h>

#define HID 1024
#define HEADS 16
#define FEAT 16
#define HD 64
#define T_LEN 1024
#define NFEAT 136   // 16 diag + 120 off-diag
#define CL 32       // chunk length
#define NC 32       // chunks per head
#define SSTATE (NFEAT * HD)  // 8704
#define PSTR 138    // padded phi stride in chunk_out (even -> aligned float2)

typedef __attribute__((ext_vector_type(8))) short short8;
typedef __attribute__((ext_vector_type(4))) float f32x4;

// upper-triangle index pair tables (i<j of 16)
__device__ const unsigned char IU_d[120] = {
    0,0,0,0,0,0,0,0,0,0,0,0,0,0,0,
    1,1,1,1,1,1,1,1,1,1,1,1,1,1,
    2,2,2,2,2,2,2,2,2,2,2,2,2,
    3,3,3,3,3,3,3,3,3,3,3,3,
    4,4,4,4,4,4,4,4,4,4,4,
    5,5,5,5,5,5,5,5,5,5,
    6,6,6,6,6,6,6,6,6,
    7,7,7,7,7,7,7,7,
    8,8,8,8,8,8,8,
    9,9,9,9,9,9,
    10,10,10,10,10,
    11,11,11,11,
    12,12,12,
    13,13,
    14};
__device__ const unsigned char JU_d[120] = {
    1,2,3,4,5,6,7,8,9,10,11,12,13,14,15,
    2,3,4,5,6,7,8,9,10,11,12,13,14,15,
    3,4,5,6,7,8,9,10,11,12,13,14,15,
    4,5,6,7,8,9,10,11,12,13,14,15,
    5,6,7,8,9,10,11,12,13,14,15,
    6,7,8,9,10,11,12,13,14,15,
    7,8,9,10,11,12,13,14,15,
    8,9,10,11,12,13,14,15,
    9,10,11,12,13,14,15,
    10,11,12,13,14,15,
    11,12,13,14,15,
    12,13,14,15,
    13,14,15,
    14,15,
    15};

// ---------------------------------------------------------------------------
// f32 <-> bf16 helpers
// ---------------------------------------------------------------------------
__device__ __forceinline__ unsigned short f2bf(float f) {
    union { float f; unsigned int u; } x;
    x.f = f;
    unsigned int u = x.u;
    unsigned int r = u + 0x7fffu + ((u >> 16) & 1u);
    return (unsigned short)(r >> 16);
}
__device__ __forceinline__ float bf2f(unsigned short s) {
    union { unsigned int u; float f; } x;
    x.u = ((unsigned int)s) << 16;
    return x.f;
}

// T2 swizzle: within each 64-col K-tile, 16B block b (0..7) of row r is
// STORED at block b ^ (r&7).  XOR involution; applied at producer stores and
// GEMM ds_reads; global_load_lds staging stays linear (rule #21).
__device__ __forceinline__ int swz_col(int row, int k) {
    return (k & ~63) | ((((k >> 3) & 7) ^ (row & 7)) << 3);
}

// ---------------------------------------------------------------------------
// Fused conversion kernel. 2-segment layouts, SWIZZLED stores (R15 verbatim).
// ---------------------------------------------------------------------------
__device__ __forceinline__ void split_store2(const float* __restrict__ in,
                                             unsigned short* __restrict__ out,
                                             int i, int rowoff) {
    float4 a = *(const float4*)&in[i];
    float4 b = *(const float4*)&in[i + 4];
    float x[8] = {a.x, a.y, a.z, a.w, b.x, b.y, b.z, b.w};
    union { unsigned short s[8]; short8 v; } hi, lo;
#pragma unroll
    for (int j = 0; j < 8; ++j) {
        hi.s[j] = f2bf(x[j]);
        lo.s[j] = f2bf(x[j] - bf2f(hi.s[j]));
    }
    int row = (i >> 10) + rowoff;
    int ks = swz_col(row, i & 1023);
    unsigned short* base = out + (size_t)row * 2048 + ks;
    *(short8*)&base[0]    = hi.v;
    *(short8*)&base[1024] = lo.v;
}

__device__ __forceinline__ void plain_store(const float* __restrict__ in,
                                            unsigned short* __restrict__ out, int i) {
    float4 a = *(const float4*)&in[i];
    float4 b = *(const float4*)&in[i + 4];
    union { unsigned short s[8]; short8 v; } o;
    o.s[0] = f2bf(a.x); o.s[1] = f2bf(a.y); o.s[2] = f2bf(a.z); o.s[3] = f2bf(a.w);
    o.s[4] = f2bf(b.x); o.s[5] = f2bf(b.y); o.s[6] = f2bf(b.z); o.s[7] = f2bf(b.w);
    int row = i >> 10;
    int ks = swz_col(row, i & 1023);
    *(short8*)&out[(size_t)row * 1024 + ks] = o.v;
}

__global__ __launch_bounds__(256) void cvt_all(const float* __restrict__ hs,
                                               const float* __restrict__ Wq,
                                               const float* __restrict__ Wk,
                                               const float* __restrict__ Wv,
                                               const float* __restrict__ Wo,
                                               unsigned short* __restrict__ hs2,
                                               unsigned short* __restrict__ wqk2,
                                               unsigned short* __restrict__ wv_b,
                                               unsigned short* __restrict__ wo_b) {
    int bx = blockIdx.x;
    int tid = threadIdx.x;
    if (bx < 512) {
        split_store2(hs, hs2, (bx * 256 + tid) * 8, 0);
    } else if (bx < 640) {
        split_store2(Wq, wqk2, ((bx - 512) * 256 + tid) * 8, 0);
    } else if (bx < 768) {
        split_store2(Wk, wqk2, ((bx - 640) * 256 + tid) * 8, 256);
    } else if (bx < 1280) {
        plain_store(Wv, wv_b, ((bx - 768) * 256 + tid) * 8);
    } else {
        plain_store(Wo, wo_b, ((bx - 1280) * 256 + tid) * 8);
    }
}

// ---------------------------------------------------------------------------
// async global->LDS copy
// ---------------------------------------------------------------------------
__device__ __forceinline__ void async_copy16(const void* g, const void* l) {
    __builtin_amdgcn_global_load_lds(
        (const __attribute__((address_space(1))) void*)(uintptr_t)g,
        (__attribute__((address_space(3))) void*)(uintptr_t)l, 16, 0, 0);
}

#define BAR_ONLY()   asm volatile("s_barrier" ::: "memory")
#define SYNC_KEEP(N) asm volatile("s_waitcnt vmcnt(" #N ")\n\ts_barrier" ::: "memory")

// ---------------------------------------------------------------------------
// BK=64, lookahead-3, 4-buffer pipelined 512-thread (8-wave) bf16 MFMA GEMM
// (R15 verbatim — pre-swizzled sources, linear staging, XOR on ds_read).
// ---------------------------------------------------------------------------
__device__ __forceinline__ void gemm_pipe512(const unsigned short* __restrict__ A,
                                             const unsigned short* __restrict__ B,
                                             void* __restrict__ Cv,
                                             int lda, int ldb, int ldc,
                                             int bm, int bn, int ntiles, int out_bf16,
                                             unsigned short (&As)[4][8192],
                                             unsigned short (&Bs)[4][8192]) {
    const int tid = threadIdx.x;
    const int wave = tid >> 6;
    const int lane = tid & 63;
    const int wr = wave >> 1;
    const int wc = wave & 1;
    const int fr = lane & 15;
    const int fq = lane >> 4;
    const int srow = tid >> 3;
    const int scol = (tid & 7) << 3;

    f32x4 acc[2][4];
#pragma unroll
    for (int i = 0; i < 2; ++i)
#pragma unroll
        for (int j = 0; j < 4; ++j) acc[i][j] = (f32x4)0.f;

    auto stage = [&](int buf, int tile) {
        const int k0 = tile << 6;
        async_copy16(&A[(size_t)(bm + srow) * lda + k0 + scol],
                     &As[buf][wave * 512]);
        async_copy16(&A[(size_t)(bm + 64 + srow) * lda + k0 + scol],
                     &As[buf][4096 + wave * 512]);
        async_copy16(&B[(size_t)(bn + srow) * ldb + k0 + scol],
                     &Bs[buf][wave * 512]);
        async_copy16(&B[(size_t)(bn + 64 + srow) * ldb + k0 + scol],
                     &Bs[buf][4096 + wave * 512]);
    };
    auto compute = [&](int buf) {
        short8 a[2][2], b[4][2];
#pragma unroll
        for (int i = 0; i < 2; ++i)
#pragma unroll
            for (int kh = 0; kh < 2; ++kh) {
                int r = wr * 32 + i * 16 + fr;
                int blk = (kh * 4 + fq) ^ (r & 7);
                a[i][kh] = *(const short8*)&As[buf][r * 64 + (blk << 3)];
            }
#pragma unroll
        for (int j = 0; j < 4; ++j)
#pragma unroll
            for (int kh = 0; kh < 2; ++kh) {
                int r = wc * 64 + j * 16 + fr;
                int blk = (kh * 4 + fq) ^ (r & 7);
                b[j][kh] = *(const short8*)&Bs[buf][r * 64 + (blk << 3)];
            }
#pragma unroll
        for (int i = 0; i < 2; ++i)
#pragma unroll
            for (int j = 0; j < 4; ++j) {
                acc[i][j] = __builtin_amdgcn_mfma_f32_16x16x32_bf16(a[i][0], b[j][0], acc[i][j], 0, 0, 0);
                acc[i][j] = __builtin_amdgcn_mfma_f32_16x16x32_bf16(a[i][1], b[j][1], acc[i][j], 0, 0, 0);
            }
    };

    stage(0, 0);
    stage(1, 1);
    stage(2, 2);
    for (int it = 0; it < ntiles - 3; ++it) {
        BAR_ONLY();
        stage((it + 3) & 3, it + 3);
        SYNC_KEEP(12);
        compute(it & 3);
    }
    SYNC_KEEP(8);
    compute((ntiles - 3) & 3);
    SYNC_KEEP(4);
    compute((ntiles - 2) & 3);
    SYNC_KEEP(0);
    compute((ntiles - 1) & 3);

#pragma unroll
    for (int i = 0; i < 2; ++i)
#pragma unroll
        for (int j = 0; j < 4; ++j) {
            int col = bn + wc * 64 + j * 16 + fr;
#pragma unroll
            for (int r = 0; r < 4; ++r) {
                int row = bm + wr * 32 + i * 16 + fq * 4 + r;
                if (out_bf16)
                    ((unsigned short*)Cv)[(size_t)row * ldc + col] = f2bf(acc[i][j][r]);
                else
                    ((float*)Cv)[(size_t)row * ldc + col] = acc[i][j][r];
            }
        }
}

// ---------------------------------------------------------------------------
// Grouped QKV GEMM, 256 blocks (full machine) x 512 threads.
//  bx<192: qk partial. seg6 = bx>>5 in 0..5 -> (s = seg6%3, khalf = seg6/3):
//          s0 hi*hi, s1 lo*hi, s2 hi*lo; khalf selects K range [0,512)/[512,1024).
//          8 K-iters each -> qk_part[seg6] (f32 [1024][512])
//  bx>=192: v = hi(hs) @ hi(Wv)^T, 16 K-iters -> v_b (bf16)
// ---------------------------------------------------------------------------
__global__ __launch_bounds__(512) void gemm_qkv(const unsigned short* __restrict__ hs2,
                                                const unsigned short* __restrict__ wqk2,
                                                const unsigned short* __restrict__ wv_b,
                                                float* __restrict__ qk_part,
                                                unsigned short* __restrict__ v_b) {
    __shared__ __align__(16) unsigned short As[4][8192];
    __shared__ __align__(16) unsigned short Bs[4][8192];
    const int bx = blockIdx.x;
    if (bx < 192) {
        int seg6 = bx >> 5, r = bx & 31;
        int s = seg6 % 3, kh = seg6 / 3;
        int bm = (r >> 2) * 128, bn = (r & 3) * 128;
        const unsigned short* A = hs2 + (s == 1 ? 1024 : 0) + kh * 512;
        const unsigned short* B = wqk2 + (s == 2 ? 1024 : 0) + kh * 512;
        gemm_pipe512(A, B, qk_part + (size_t)seg6 * (1024 * 512),
                     2048, 2048, 512, bm, bn, 8, 0, As, Bs);
    } else {
        int r = bx - 192;
        int bm = (r >> 3) * 128, bn = (r & 7) * 128;
        gemm_pipe512(hs2, wv_b, v_b, 2048, 1024, 1024, bm, bn, 16, 1, As, Bs);
    }
}

// ---------------------------------------------------------------------------
// Wo GEMM: 64 blocks x 16 K-iters, 512 threads, writes out directly.
// ---------------------------------------------------------------------------
__global__ __launch_bounds__(512) void gemm_wo(const unsigned short* __restrict__ y_b,
                                               const unsigned short* __restrict__ wo_b,
                                               float* __restrict__ out) {
    __shared__ __align__(16) unsigned short As[4][8192];
    __shared__ __align__(16) unsigned short Bs[4][8192];
    const int r = blockIdx.x;
    const int bm = (r >> 3) * 128, bn = (r & 7) * 128;
    gemm_pipe512(y_b, wo_b, out, 1024, 1024, 1024, bm, bn, 16, 0, As, Bs);
}

// ---------------------------------------------------------------------------
// LN of one row of q/k (summing 6 split-K partials) -> xn row in LDS.
// ---------------------------------------------------------------------------
__device__ __forceinline__ void ln_row_to_lds(const float* __restrict__ qk_part,
                                              int col0, int h, int t,
                                              const float* __restrict__ gamma,
                                              const float* __restrict__ beta,
                                              float* __restrict__ xn_row) {
    const float* base = qk_part + (size_t)t * 512 + col0 + h * FEAT;
    float x[16];
    float mu = 0.f;
#pragma unroll
    for (int f = 0; f < 16; ++f) {
        float s = 0.f;
#pragma unroll
        for (int j = 0; j < 6; ++j) s += base[f + (size_t)j * 524288];
        x[f] = s;
        mu += s;
    }
    mu *= (1.f / 16.f);
    float var = 0.f;
#pragma unroll
    for (int f = 0; f < 16; ++f) {
        float d = x[f] - mu;
        var += d * d;
    }
    var *= (1.f / 16.f);
    float rstd = rsqrtf(var + 1e-5f);
#pragma unroll
    for (int f = 0; f < 16; ++f)
        xn_row[f] = (x[f] - mu) * rstd * gamma[f] + beta[f];
}

// ---------------------------------------------------------------------------
// Phase 1: per-chunk KV sums + Z sums, feature map fused.
// ---------------------------------------------------------------------------
__global__ __launch_bounds__(256) void chunk_kv(const float* __restrict__ qk_part,
                                                const unsigned short* __restrict__ v_b,
                                                const float* __restrict__ gamma,
                                                const float* __restrict__ beta,
                                                float* __restrict__ KV,
                                                float* __restrict__ Z) {
    const int c = blockIdx.x;
    const int h = blockIdx.y;
    const int tid = threadIdx.x;
    __shared__ float xn_s[CL][17];
    __shared__ float pk_s[CL * NFEAT];
    __shared__ unsigned char iu_s[120], ju_s[120];

    const int d = tid & 63;
    const int fg = tid >> 6;

    if (tid < 120) { iu_s[tid] = IU_d[tid]; ju_s[tid] = JU_d[tid]; }

    float v[CL];
#pragma unroll
    for (int t = 0; t < CL; ++t)
        v[t] = bf2f(v_b[(size_t)(c * CL + t) * 1024 + h * HD + d]);

    if (tid < CL)
        ln_row_to_lds(qk_part, 256, h, c * CL + tid, gamma, beta, xn_s[tid]);
    __syncthreads();

    {
        int r = tid >> 3, p = tid & 7;
        const float c1 = 0.25f;
        const float c2 = 0.35355339059327373f;
#pragma unroll
        for (int n = 0; n < 17; ++n) {
            int idx = p * 17 + n;
            float val;
            if (idx < 16) {
                float a = xn_s[r][idx];
                val = a * a * c1;
            } else {
                val = xn_s[r][iu_s[idx - 16]] * xn_s[r][ju_s[idx - 16]] * c2;
            }
            pk_s[r * NFEAT + idx] = val;
        }
    }
    __syncthreads();

    float* kv_out = KV + ((size_t)(h * NC + c)) * SSTATE;
    float* z_out = Z + ((size_t)(h * NC + c)) * NFEAT;
#pragma unroll
    for (int np = 0; np < 17; ++np) {
        int f = fg * 34 + 2 * np;
        float acc0 = 0.f, acc1 = 0.f, z0 = 0.f, z1 = 0.f;
#pragma unroll
        for (int t = 0; t < CL; ++t) {
            float2 pk = *(const float2*)&pk_s[t * NFEAT + f];
            acc0 += pk.x * v[t];
            acc1 += pk.y * v[t];
            z0 += pk.x;
            z1 += pk.y;
        }
        kv_out[(f + 0) * HD + d] = acc0;
        kv_out[(f + 1) * HD + d] = acc1;
        if (d == 0) { z_out[f] = z0; z_out[f + 1] = z1; }
    }
}

// ---------------------------------------------------------------------------
// Phase 2: exclusive prefix scan over chunks (R8 verbatim).
// ---------------------------------------------------------------------------
__global__ __launch_bounds__(256) void chunk_scan(float* __restrict__ KV,
                                                  float* __restrict__ Z) {
    const int bx = blockIdx.x;
    const int h = blockIdx.y;
    const int tid = threadIdx.x;
    if (bx < 34) {
        float* base = KV + (size_t)h * NC * SSTATE + bx * 256 + tid;
        float val[NC];
#pragma unroll
        for (int c = 0; c < NC; ++c) val[c] = base[(size_t)c * SSTATE];
        float run = 0.f;
#pragma unroll
        for (int c = 0; c < NC; ++c) {
            float t = val[c];
            val[c] = run;
            run += t;
        }
#pragma unroll
        for (int c = 0; c < NC; ++c) base[(size_t)c * SSTATE] = val[c];
    } else if (tid < NFEAT) {
        float* base = Z + (size_t)h * NC * NFEAT + tid;
        float val[NC];
#pragma unroll
        for (int c = 0; c < NC; ++c) val[c] = base[(size_t)c * NFEAT];
        float run = 0.f;
#pragma unroll
        for (int c = 0; c < NC; ++c) {
            float t = val[c];
            val[c] = run;
            run += t;
        }
#pragma unroll
        for (int c = 0; c < NC; ++c) base[(size_t)c * NFEAT] = val[c];
    }
}

// ---------------------------------------------------------------------------
// Phase 3: per-chunk output; PSTR=138 padded phi, float2 LDS reads;
// y_b stored SWIZZLED (gemm_wo A-input).
// ---------------------------------------------------------------------------
__global__ __launch_bounds__(256) void chunk_out(const float* __restrict__ qk_part,
                                                 const unsigned short* __restrict__ v_b,
                                                 const float* __restrict__ gamma,
                                                 const float* __restrict__ beta,
                                                 const float* __restrict__ KV,
                                                 const float* __restrict__ Z,
                                                 unsigned short* __restrict__ y_b) {
    const int c = blockIdx.x;
    const int h = blockIdx.y;
    const int tid = threadIdx.x;

    __shared__ float xnq_s[CL][17];
    __shared__ float xnk_s[CL][17];
    __shared__ float pq_s[CL * PSTR];
    __shared__ float pk_s[CL * PSTR];
    __shared__ float A_s[CL * CL];
    __shared__ unsigned char iu_s[120], ju_s[120];

    const int d = tid & 63;
    const int tg = tid >> 6;

    if (tid < 120) { iu_s[tid] = IU_d[tid]; ju_s[tid] = JU_d[tid]; }

    float v[CL];
#pragma unroll
    for (int t = 0; t < CL; ++t)
        v[t] = bf2f(v_b[(size_t)(c * CL + t) * 1024 + h * HD + d]);

    if (tid < 64) {
        int mat = tid >> 5;
        int r = tid & 31;
        ln_row_to_lds(qk_part, mat ? 256 : 0, h, c * CL + r, gamma, beta,
                      mat ? xnk_s[r] : xnq_s[r]);
    }
    for (int e = tid; e < CL * CL; e += 256) A_s[e] = 0.f;
    __syncthreads();

    {
        int mat = tid >> 7;
        int r = (tid & 127) >> 2;
        int p = tid & 3;
        const float (*xn)[17] = mat ? xnk_s : xnq_s;
        float* dst = (mat ? pk_s : pq_s) + (size_t)r * PSTR;
        const float c1 = 0.25f;
        const float c2 = 0.35355339059327373f;
#pragma unroll
        for (int n = 0; n < 34; ++n) {
            int idx = p * 34 + n;
            float val;
            if (idx < 16) {
                float a = xn[r][idx];
                val = a * a * c1;
            } else {
                val = xn[r][iu_s[idx - 16]] * xn[r][ju_s[idx - 16]] * c2;
            }
            dst[idx] = val;
        }
    }
    __syncthreads();

    // A lower triangle: float2 reads (PSTR even, f even -> aligned)
    for (int e = tid; e < 528; e += 256) {
        int t = (int)((sqrtf(8.f * e + 1.f) - 1.f) * 0.5f);
        int s = e - ((t * (t + 1)) >> 1);
        float acc = 0.f;
#pragma unroll 4
        for (int f = 0; f < NFEAT; f += 2) {
            float2 q2 = *(const float2*)&pq_s[t * PSTR + f];
            float2 k2 = *(const float2*)&pk_s[s * PSTR + f];
            acc += q2.x * k2.x + q2.y * k2.y;
        }
        A_s[t * CL + s] = acc;
    }
    __syncthreads();

    const float* kv_pref = KV + ((size_t)(h * NC + c)) * SSTATE;
    const float* z_pref = Z + ((size_t)(h * NC + c)) * NFEAT;

    float num[8], den[8];
#pragma unroll
    for (int i = 0; i < 8; ++i) { num[i] = 0.f; den[i] = 0.f; }

#pragma unroll 4
    for (int f = 0; f < NFEAT; f += 2) {
        float sp0 = kv_pref[f * HD + d];
        float sp1 = kv_pref[(f + 1) * HD + d];
        float zp0 = z_pref[f];
        float zp1 = z_pref[f + 1];
#pragma unroll
        for (int i = 0; i < 8; ++i) {
            float2 pq2 = *(const float2*)&pq_s[(tg * 8 + i) * PSTR + f];
            num[i] += pq2.x * sp0 + pq2.y * sp1;
            den[i] += pq2.x * zp0 + pq2.y * zp1;
        }
    }
#pragma unroll
    for (int s = 0; s < CL; ++s) {
        float vv = v[s];
#pragma unroll
        for (int i = 0; i < 8; ++i) {
            float a = A_s[(tg * 8 + i) * CL + s];
            num[i] += a * vv;
            den[i] += a;
        }
    }
#pragma unroll
    for (int i = 0; i < 8; ++i) {
        int t = c * CL + tg * 8 + i;
        int ds = ((((d >> 3) ^ (t & 7))) << 3) | (d & 7);
        y_b[(size_t)t * 1024 + h * HD + ds] = f2bf(num[i] / (den[i] + 1e-5f));
    }
}

extern "C" void kernel_launch(void* const* d_in, const int* in_sizes, int n_in,
                              void* d_out, int out_size, void* d_ws, size_t ws_size,
                              hipStream_t stream) {
    const float* hs    = (const float*)d_in[0];
    const float* Wq    = (const float*)d_in[1];
    const float* Wk    = (const float*)d_in[2];
    const float* Wv    = (const float*)d_in[3];
    const float* Wo    = (const float*)d_in[4];
    const float* gamma = (const float*)d_in[5];
    const float* beta  = (const float*)d_in[6];
    float* out = (float*)d_out;

    float* ws = (float*)d_ws;
    float* qk_part = ws;                                   // 6*1024*512
    float* KV      = qk_part + 6 * 1024 * 512;             // 16*32*8704
    float* Z       = KV + (size_t)HEADS * NC * SSTATE;     // 16*32*136
    unsigned short* hs2  = (unsigned short*)(Z + HEADS * NC * NFEAT);  // 1024*2048
    unsigned short* wqk2 = hs2 + (size_t)1024 * 2048;      // 512*2048
    unsigned short* wv_b = wqk2 + (size_t)512 * 2048;      // 1024*1024
    unsigned short* wo_b = wv_b + (size_t)1024 * 1024;     // 1024*1024
    unsigned short* v_b  = wo_b + (size_t)1024 * 1024;     // 1024*1024
    unsigned short* y_b  = v_b + (size_t)1024 * 1024;      // 1024*1024

    cvt_all<<<1792, dim3(256), 0, stream>>>(hs, Wq, Wk, Wv, Wo, hs2, wqk2, wv_b, wo_b);

    gemm_qkv<<<256, dim3(512), 0, stream>>>(hs2, wqk2, wv_b, qk_part, v_b);

    chunk_kv<<<dim3(NC, HEADS), dim3(256), 0, stream>>>(qk_part, v_b, gamma, beta, KV, Z);
    chunk_scan<<<dim3(35, HEADS), dim3(256), 0, stream>>>(KV, Z);
    chunk_out<<<dim3(NC, HEADS), dim3(256), 0, stream>>>(qk_part, v_b, gamma, beta, KV, Z, y_b);

    gemm_wo<<<64, dim3(512), 0, stream>>>(y_b, wo_b, out);
}

// Round 17
// 82.347 us; speedup vs baseline: 1.2445x; 1.2445x over previous
//
#include <hip/hip_runtime.h>
#include <hip/hip_bf16.h>

#define HID 1024
#define HEADS 16
#define FEAT 16
#define HD 64
#define T_LEN 1024
#define NFEAT 136   // 16 diag + 120 off-diag
#define CL 32       // chunk length
#define NC 32       // chunks per head
#define SSTATE (NFEAT * HD)  // 8704

typedef __attribute__((ext_vector_type(8))) short short8;
typedef __attribute__((ext_vector_type(4))) float f32x4;

// upper-triangle index pair tables (i<j of 16)
__device__ const unsigned char IU_d[120] = {
    0,0,0,0,0,0,0,0,0,0,0,0,0,0,0,
    1,1,1,1,1,1,1,1,1,1,1,1,1,1,
    2,2,2,2,2,2,2,2,2,2,2,2,2,
    3,3,3,3,3,3,3,3,3,3,3,3,
    4,4,4,4,4,4,4,4,4,4,4,
    5,5,5,5,5,5,5,5,5,5,
    6,6,6,6,6,6,6,6,6,
    7,7,7,7,7,7,7,7,
    8,8,8,8,8,8,8,
    9,9,9,9,9,9,
    10,10,10,10,10,
    11,11,11,11,
    12,12,12,
    13,13,
    14};
__device__ const unsigned char JU_d[120] = {
    1,2,3,4,5,6,7,8,9,10,11,12,13,14,15,
    2,3,4,5,6,7,8,9,10,11,12,13,14,15,
    3,4,5,6,7,8,9,10,11,12,13,14,15,
    4,5,6,7,8,9,10,11,12,13,14,15,
    5,6,7,8,9,10,11,12,13,14,15,
    6,7,8,9,10,11,12,13,14,15,
    7,8,9,10,11,12,13,14,15,
    8,9,10,11,12,13,14,15,
    9,10,11,12,13,14,15,
    10,11,12,13,14,15,
    11,12,13,14,15,
    12,13,14,15,
    13,14,15,
    14,15,
    15};

// ---------------------------------------------------------------------------
// f32 <-> bf16 helpers
// ---------------------------------------------------------------------------
__device__ __forceinline__ unsigned short f2bf(float f) {
    union { float f; unsigned int u; } x;
    x.f = f;
    unsigned int u = x.u;
    unsigned int r = u + 0x7fffu + ((u >> 16) & 1u);
    return (unsigned short)(r >> 16);
}
__device__ __forceinline__ float bf2f(unsigned short s) {
    union { unsigned int u; float f; } x;
    x.u = ((unsigned int)s) << 16;
    return x.f;
}

// T2 swizzle: within each 64-col K-tile, 16B block b (0..7) of row r is
// STORED at block b ^ (r&7).
__device__ __forceinline__ int swz_col(int row, int k) {
    return (k & ~63) | ((((k >> 3) & 7) ^ (row & 7)) << 3);
}

// ---------------------------------------------------------------------------
// Fused conversion kernel (R15 verbatim).
// ---------------------------------------------------------------------------
__device__ __forceinline__ void split_store2(const float* __restrict__ in,
                                             unsigned short* __restrict__ out,
                                             int i, int rowoff) {
    float4 a = *(const float4*)&in[i];
    float4 b = *(const float4*)&in[i + 4];
    float x[8] = {a.x, a.y, a.z, a.w, b.x, b.y, b.z, b.w};
    union { unsigned short s[8]; short8 v; } hi, lo;
#pragma unroll
    for (int j = 0; j < 8; ++j) {
        hi.s[j] = f2bf(x[j]);
        lo.s[j] = f2bf(x[j] - bf2f(hi.s[j]));
    }
    int row = (i >> 10) + rowoff;
    int ks = swz_col(row, i & 1023);
    unsigned short* base = out + (size_t)row * 2048 + ks;
    *(short8*)&base[0]    = hi.v;
    *(short8*)&base[1024] = lo.v;
}

__device__ __forceinline__ void plain_store(const float* __restrict__ in,
                                            unsigned short* __restrict__ out, int i) {
    float4 a = *(const float4*)&in[i];
    float4 b = *(const float4*)&in[i + 4];
    union { unsigned short s[8]; short8 v; } o;
    o.s[0] = f2bf(a.x); o.s[1] = f2bf(a.y); o.s[2] = f2bf(a.z); o.s[3] = f2bf(a.w);
    o.s[4] = f2bf(b.x); o.s[5] = f2bf(b.y); o.s[6] = f2bf(b.z); o.s[7] = f2bf(b.w);
    int row = i >> 10;
    int ks = swz_col(row, i & 1023);
    *(short8*)&out[(size_t)row * 1024 + ks] = o.v;
}

__global__ __launch_bounds__(256) void cvt_all(const float* __restrict__ hs,
                                               const float* __restrict__ Wq,
                                               const float* __restrict__ Wk,
                                               const float* __restrict__ Wv,
                                               const float* __restrict__ Wo,
                                               unsigned short* __restrict__ hs2,
                                               unsigned short* __restrict__ wqk2,
                                               unsigned short* __restrict__ wv_b,
                                               unsigned short* __restrict__ wo_b) {
    int bx = blockIdx.x;
    int tid = threadIdx.x;
    if (bx < 512) {
        split_store2(hs, hs2, (bx * 256 + tid) * 8, 0);
    } else if (bx < 640) {
        split_store2(Wq, wqk2, ((bx - 512) * 256 + tid) * 8, 0);
    } else if (bx < 768) {
        split_store2(Wk, wqk2, ((bx - 640) * 256 + tid) * 8, 256);
    } else if (bx < 1280) {
        plain_store(Wv, wv_b, ((bx - 768) * 256 + tid) * 8);
    } else {
        plain_store(Wo, wo_b, ((bx - 1280) * 256 + tid) * 8);
    }
}

// ---------------------------------------------------------------------------
// async global->LDS copy
// ---------------------------------------------------------------------------
__device__ __forceinline__ void async_copy16(const void* g, const void* l) {
    __builtin_amdgcn_global_load_lds(
        (const __attribute__((address_space(1))) void*)(uintptr_t)g,
        (__attribute__((address_space(3))) void*)(uintptr_t)l, 16, 0, 0);
}

#define BAR_ONLY()   asm volatile("s_barrier" ::: "memory")
#define SYNC_KEEP(N) asm volatile("s_waitcnt vmcnt(" #N ")\n\ts_barrier" ::: "memory")

// ---------------------------------------------------------------------------
// BK=64, lookahead-3, 4-buffer pipelined 512-thread (8-wave) bf16 MFMA GEMM
// (R15 verbatim).
// ---------------------------------------------------------------------------
__device__ __forceinline__ void gemm_pipe512(const unsigned short* __restrict__ A,
                                             const unsigned short* __restrict__ B,
                                             void* __restrict__ Cv,
                                             int lda, int ldb, int ldc,
                                             int bm, int bn, int ntiles, int out_bf16,
                                             unsigned short (&As)[4][8192],
                                             unsigned short (&Bs)[4][8192]) {
    const int tid = threadIdx.x;
    const int wave = tid >> 6;
    const int lane = tid & 63;
    const int wr = wave >> 1;
    const int wc = wave & 1;
    const int fr = lane & 15;
    const int fq = lane >> 4;
    const int srow = tid >> 3;
    const int scol = (tid & 7) << 3;

    f32x4 acc[2][4];
#pragma unroll
    for (int i = 0; i < 2; ++i)
#pragma unroll
        for (int j = 0; j < 4; ++j) acc[i][j] = (f32x4)0.f;

    auto stage = [&](int buf, int tile) {
        const int k0 = tile << 6;
        async_copy16(&A[(size_t)(bm + srow) * lda + k0 + scol],
                     &As[buf][wave * 512]);
        async_copy16(&A[(size_t)(bm + 64 + srow) * lda + k0 + scol],
                     &As[buf][4096 + wave * 512]);
        async_copy16(&B[(size_t)(bn + srow) * ldb + k0 + scol],
                     &Bs[buf][wave * 512]);
        async_copy16(&B[(size_t)(bn + 64 + srow) * ldb + k0 + scol],
                     &Bs[buf][4096 + wave * 512]);
    };
    auto compute = [&](int buf) {
        short8 a[2][2], b[4][2];
#pragma unroll
        for (int i = 0; i < 2; ++i)
#pragma unroll
            for (int kh = 0; kh < 2; ++kh) {
                int r = wr * 32 + i * 16 + fr;
                int blk = (kh * 4 + fq) ^ (r & 7);
                a[i][kh] = *(const short8*)&As[buf][r * 64 + (blk << 3)];
            }
#pragma unroll
        for (int j = 0; j < 4; ++j)
#pragma unroll
            for (int kh = 0; kh < 2; ++kh) {
                int r = wc * 64 + j * 16 + fr;
                int blk = (kh * 4 + fq) ^ (r & 7);
                b[j][kh] = *(const short8*)&Bs[buf][r * 64 + (blk << 3)];
            }
#pragma unroll
        for (int i = 0; i < 2; ++i)
#pragma unroll
            for (int j = 0; j < 4; ++j) {
                acc[i][j] = __builtin_amdgcn_mfma_f32_16x16x32_bf16(a[i][0], b[j][0], acc[i][j], 0, 0, 0);
                acc[i][j] = __builtin_amdgcn_mfma_f32_16x16x32_bf16(a[i][1], b[j][1], acc[i][j], 0, 0, 0);
            }
    };

    stage(0, 0);
    stage(1, 1);
    stage(2, 2);
    for (int it = 0; it < ntiles - 3; ++it) {
        BAR_ONLY();
        stage((it + 3) & 3, it + 3);
        SYNC_KEEP(12);
        compute(it & 3);
    }
    SYNC_KEEP(8);
    compute((ntiles - 3) & 3);
    SYNC_KEEP(4);
    compute((ntiles - 2) & 3);
    SYNC_KEEP(0);
    compute((ntiles - 1) & 3);

#pragma unroll
    for (int i = 0; i < 2; ++i)
#pragma unroll
        for (int j = 0; j < 4; ++j) {
            int col = bn + wc * 64 + j * 16 + fr;
#pragma unroll
            for (int r = 0; r < 4; ++r) {
                int row = bm + wr * 32 + i * 16 + fq * 4 + r;
                if (out_bf16)
                    ((unsigned short*)Cv)[(size_t)row * ldc + col] = f2bf(acc[i][j][r]);
                else
                    ((float*)Cv)[(size_t)row * ldc + col] = acc[i][j][r];
            }
        }
}

// ---------------------------------------------------------------------------
// Grouped QKV GEMM, 160 blocks x 16 K-iters (R15 verbatim).
// ---------------------------------------------------------------------------
__global__ __launch_bounds__(512) void gemm_qkv(const unsigned short* __restrict__ hs2,
                                                const unsigned short* __restrict__ wqk2,
                                                const unsigned short* __restrict__ wv_b,
                                                float* __restrict__ qk_part,
                                                unsigned short* __restrict__ v_b) {
    __shared__ __align__(16) unsigned short As[4][8192];
    __shared__ __align__(16) unsigned short Bs[4][8192];
    const int bx = blockIdx.x;
    if (bx < 96) {
        int seg = bx >> 5, r = bx & 31;
        int bm = (r >> 2) * 128, bn = (r & 3) * 128;
        const unsigned short* A = hs2 + (seg == 1 ? 1024 : 0);
        const unsigned short* B = wqk2 + (seg == 2 ? 1024 : 0);
        gemm_pipe512(A, B, qk_part + (size_t)seg * (1024 * 512),
                     2048, 2048, 512, bm, bn, 16, 0, As, Bs);
    } else {
        int r = bx - 96;
        int bm = (r >> 3) * 128, bn = (r & 7) * 128;
        gemm_pipe512(hs2, wv_b, v_b, 2048, 1024, 1024, bm, bn, 16, 1, As, Bs);
    }
}

// ---------------------------------------------------------------------------
// Wo GEMM (R15 verbatim).
// ---------------------------------------------------------------------------
__global__ __launch_bounds__(512) void gemm_wo(const unsigned short* __restrict__ y_b,
                                               const unsigned short* __restrict__ wo_b,
                                               float* __restrict__ out) {
    __shared__ __align__(16) unsigned short As[4][8192];
    __shared__ __align__(16) unsigned short Bs[4][8192];
    const int r = blockIdx.x;
    const int bm = (r >> 3) * 128, bn = (r & 7) * 128;
    gemm_pipe512(y_b, wo_b, out, 1024, 1024, 1024, bm, bn, 16, 0, As, Bs);
}

// ---------------------------------------------------------------------------
// LN of one row of q/k (summing 3 split partials) -> xn row in LDS.
// ---------------------------------------------------------------------------
__device__ __forceinline__ void ln_row_to_lds(const float* __restrict__ qk_part,
                                              int col0, int h, int t,
                                              const float* __restrict__ gamma,
                                              const float* __restrict__ beta,
                                              float* __restrict__ xn_row) {
    const float* base = qk_part + (size_t)t * 512 + col0 + h * FEAT;
    float x[16];
    float mu = 0.f;
#pragma unroll
    for (int f = 0; f < 16; ++f) {
        x[f] = base[f] + base[f + 524288] + base[f + 1048576];
        mu += x[f];
    }
    mu *= (1.f / 16.f);
    float var = 0.f;
#pragma unroll
    for (int f = 0; f < 16; ++f) {
        float d = x[f] - mu;
        var += d * d;
    }
    var *= (1.f / 16.f);
    float rstd = rsqrtf(var + 1e-5f);
#pragma unroll
    for (int f = 0; f < 16; ++f)
        xn_row[f] = (x[f] - mu) * rstd * gamma[f] + beta[f];
}

// ---------------------------------------------------------------------------
// Phase 1: per-chunk KV sums + Z sums (R15 verbatim).
// ---------------------------------------------------------------------------
__global__ __launch_bounds__(256) void chunk_kv(const float* __restrict__ qk_part,
                                                const unsigned short* __restrict__ v_b,
                                                const float* __restrict__ gamma,
                                                const float* __restrict__ beta,
                                                float* __restrict__ KV,
                                                float* __restrict__ Z) {
    const int c = blockIdx.x;
    const int h = blockIdx.y;
    const int tid = threadIdx.x;
    __shared__ float xn_s[CL][17];
    __shared__ float pk_s[CL * NFEAT];
    __shared__ unsigned char iu_s[120], ju_s[120];

    const int d = tid & 63;
    const int fg = tid >> 6;

    if (tid < 120) { iu_s[tid] = IU_d[tid]; ju_s[tid] = JU_d[tid]; }

    float v[CL];
#pragma unroll
    for (int t = 0; t < CL; ++t)
        v[t] = bf2f(v_b[(size_t)(c * CL + t) * 1024 + h * HD + d]);

    if (tid < CL)
        ln_row_to_lds(qk_part, 256, h, c * CL + tid, gamma, beta, xn_s[tid]);
    __syncthreads();

    {
        int r = tid >> 3, p = tid & 7;
        const float c1 = 0.25f;
        const float c2 = 0.35355339059327373f;
#pragma unroll
        for (int n = 0; n < 17; ++n) {
            int idx = p * 17 + n;
            float val;
            if (idx < 16) {
                float a = xn_s[r][idx];
                val = a * a * c1;
            } else {
                val = xn_s[r][iu_s[idx - 16]] * xn_s[r][ju_s[idx - 16]] * c2;
            }
            pk_s[r * NFEAT + idx] = val;
        }
    }
    __syncthreads();

    float* kv_out = KV + ((size_t)(h * NC + c)) * SSTATE;
    float* z_out = Z + ((size_t)(h * NC + c)) * NFEAT;
#pragma unroll
    for (int np = 0; np < 17; ++np) {
        int f = fg * 34 + 2 * np;
        float acc0 = 0.f, acc1 = 0.f, z0 = 0.f, z1 = 0.f;
#pragma unroll
        for (int t = 0; t < CL; ++t) {
            float2 pk = *(const float2*)&pk_s[t * NFEAT + f];
            acc0 += pk.x * v[t];
            acc1 += pk.y * v[t];
            z0 += pk.x;
            z1 += pk.y;
        }
        kv_out[(f + 0) * HD + d] = acc0;
        kv_out[(f + 1) * HD + d] = acc1;
        if (d == 0) { z_out[f] = z0; z_out[f + 1] = z1; }
    }
}

// ---------------------------------------------------------------------------
// Phase 2: exclusive prefix scan over chunks (R15 verbatim).
// ---------------------------------------------------------------------------
__global__ __launch_bounds__(256) void chunk_scan(float* __restrict__ KV,
                                                  float* __restrict__ Z) {
    const int bx = blockIdx.x;
    const int h = blockIdx.y;
    const int tid = threadIdx.x;
    if (bx < 34) {
        float* base = KV + (size_t)h * NC * SSTATE + bx * 256 + tid;
        float val[NC];
#pragma unroll
        for (int c = 0; c < NC; ++c) val[c] = base[(size_t)c * SSTATE];
        float run = 0.f;
#pragma unroll
        for (int c = 0; c < NC; ++c) {
            float t = val[c];
            val[c] = run;
            run += t;
        }
#pragma unroll
        for (int c = 0; c < NC; ++c) base[(size_t)c * SSTATE] = val[c];
    } else if (tid < NFEAT) {
        float* base = Z + (size_t)h * NC * NFEAT + tid;
        float val[NC];
#pragma unroll
        for (int c = 0; c < NC; ++c) val[c] = base[(size_t)c * NFEAT];
        float run = 0.f;
#pragma unroll
        for (int c = 0; c < NC; ++c) {
            float t = val[c];
            val[c] = run;
            run += t;
        }
#pragma unroll
        for (int c = 0; c < NC; ++c) base[(size_t)c * NFEAT] = val[c];
    }
}

// ---------------------------------------------------------------------------
// Phase 3: per-chunk output. NEW: kv_pref/z_pref prefetched to LDS via
// global_load_lds at kernel start, hidden under LN + feature + A phases
// (T14: issue-early, consume-late). num/den reads LDS (conflict-free).
// ---------------------------------------------------------------------------
__global__ __launch_bounds__(256) void chunk_out(const float* __restrict__ qk_part,
                                                 const unsigned short* __restrict__ v_b,
                                                 const float* __restrict__ gamma,
                                                 const float* __restrict__ beta,
                                                 const float* __restrict__ KV,
                                                 const float* __restrict__ Z,
                                                 unsigned short* __restrict__ y_b) {
    const int c = blockIdx.x;
    const int h = blockIdx.y;
    const int tid = threadIdx.x;
    const int wave = tid >> 6;

    __shared__ float xnq_s[CL][17];
    __shared__ float xnk_s[CL][17];
    __shared__ float pq_s[CL * 137];
    __shared__ float pk_s[CL * 137];
    __shared__ float A_s[CL * CL];
    __shared__ __align__(16) float kv_s[SSTATE];   // 34816 B
    __shared__ __align__(16) float z_s[NFEAT];
    __shared__ unsigned char iu_s[120], ju_s[120];

    const int d = tid & 63;
    const int tg = tid >> 6;

    const float* kv_pref = KV + ((size_t)(h * NC + c)) * SSTATE;
    const float* z_pref = Z + ((size_t)(h * NC + c)) * NFEAT;

    // ---- issue KV/Z prefetch FIRST (DMA; lands before the vmcnt(0) below) ----
#pragma unroll
    for (int s = 0; s < 8; ++s)
        async_copy16(&kv_pref[(s * 256 + tid) * 4], &kv_s[s * 1024 + wave * 256]);
    if (tid < 128)                                   // waves 0,1 full
        async_copy16(&kv_pref[(2048 + tid) * 4], &kv_s[8192 + wave * 256]);
    if (wave == 0 && (tid & 63) < 34)                // 34 x 16B = 136 floats
        async_copy16(&z_pref[(tid & 63) * 4], &z_s[0]);

    if (tid < 120) { iu_s[tid] = IU_d[tid]; ju_s[tid] = JU_d[tid]; }

    float v[CL];
#pragma unroll
    for (int t = 0; t < CL; ++t)
        v[t] = bf2f(v_b[(size_t)(c * CL + t) * 1024 + h * HD + d]);

    if (tid < 64) {
        int mat = tid >> 5;
        int r = tid & 31;
        ln_row_to_lds(qk_part, mat ? 256 : 0, h, c * CL + r, gamma, beta,
                      mat ? xnk_s[r] : xnq_s[r]);
    }
    for (int e = tid; e < CL * CL; e += 256) A_s[e] = 0.f;
    __syncthreads();

    {
        int mat = tid >> 7;
        int r = (tid & 127) >> 2;
        int p = tid & 3;
        const float (*xn)[17] = mat ? xnk_s : xnq_s;
        float* dst = (mat ? pk_s : pq_s) + (size_t)r * 137;
        const float c1 = 0.25f;
        const float c2 = 0.35355339059327373f;
#pragma unroll
        for (int n = 0; n < 34; ++n) {
            int idx = p * 34 + n;
            float val;
            if (idx < 16) {
                float a = xn[r][idx];
                val = a * a * c1;
            } else {
                val = xn[r][iu_s[idx - 16]] * xn[r][ju_s[idx - 16]] * c2;
            }
            dst[idx] = val;
        }
    }
    __syncthreads();

    for (int e = tid; e < 528; e += 256) {
        int t = (int)((sqrtf(8.f * e + 1.f) - 1.f) * 0.5f);
        int s = e - ((t * (t + 1)) >> 1);
        float acc = 0.f;
#pragma unroll 8
        for (int f = 0; f < NFEAT; ++f)
            acc += pq_s[t * 137 + f] * pk_s[s * 137 + f];
        A_s[t * CL + s] = acc;
    }
    // prefetch landed (each wave waits its own DMAs, then all sync)
    asm volatile("s_waitcnt vmcnt(0)" ::: "memory");
    __syncthreads();

    float num[8], den[8];
#pragma unroll
    for (int i = 0; i < 8; ++i) { num[i] = 0.f; den[i] = 0.f; }

#pragma unroll 8
    for (int f = 0; f < NFEAT; ++f) {
        float sp = kv_s[f * HD + d];     // LDS: lanes consecutive, no conflict
        float zp = z_s[f];               // broadcast
#pragma unroll
        for (int i = 0; i < 8; ++i) {
            float pq = pq_s[(tg * 8 + i) * 137 + f];
            num[i] += pq * sp;
            den[i] += pq * zp;
        }
    }
#pragma unroll
    for (int s = 0; s < CL; ++s) {
        float vv = v[s];
#pragma unroll
        for (int i = 0; i < 8; ++i) {
            float a = A_s[(tg * 8 + i) * CL + s];
            num[i] += a * vv;
            den[i] += a;
        }
    }
#pragma unroll
    for (int i = 0; i < 8; ++i) {
        int t = c * CL + tg * 8 + i;
        int ds = ((((d >> 3) ^ (t & 7))) << 3) | (d & 7);
        y_b[(size_t)t * 1024 + h * HD + ds] = f2bf(num[i] / (den[i] + 1e-5f));
    }
}

extern "C" void kernel_launch(void* const* d_in, const int* in_sizes, int n_in,
                              void* d_out, int out_size, void* d_ws, size_t ws_size,
                              hipStream_t stream) {
    const float* hs    = (const float*)d_in[0];
    const float* Wq    = (const float*)d_in[1];
    const float* Wk    = (const float*)d_in[2];
    const float* Wv    = (const float*)d_in[3];
    const float* Wo    = (const float*)d_in[4];
    const float* gamma = (const float*)d_in[5];
    const float* beta  = (const float*)d_in[6];
    float* out = (float*)d_out;

    float* ws = (float*)d_ws;
    float* qk_part = ws;                                   // 3*1024*512
    float* KV      = qk_part + 3 * 1024 * 512;             // 16*32*8704
    float* Z       = KV + (size_t)HEADS * NC * SSTATE;     // 16*32*136
    unsigned short* hs2  = (unsigned short*)(Z + HEADS * NC * NFEAT);  // 1024*2048
    unsigned short* wqk2 = hs2 + (size_t)1024 * 2048;      // 512*2048
    unsigned short* wv_b = wqk2 + (size_t)512 * 2048;      // 1024*1024
    unsigned short* wo_b = wv_b + (size_t)1024 * 1024;     // 1024*1024
    unsigned short* v_b  = wo_b + (size_t)1024 * 1024;     // 1024*1024
    unsigned short* y_b  = v_b + (size_t)1024 * 1024;      // 1024*1024

    cvt_all<<<1792, dim3(256), 0, stream>>>(hs, Wq, Wk, Wv, Wo, hs2, wqk2, wv_b, wo_b);

    gemm_qkv<<<160, dim3(512), 0, stream>>>(hs2, wqk2, wv_b, qk_part, v_b);

    chunk_kv<<<dim3(NC, HEADS), dim3(256), 0, stream>>>(qk_part, v_b, gamma, beta, KV, Z);
    chunk_scan<<<dim3(35, HEADS), dim3(256), 0, stream>>>(KV, Z);
    chunk_out<<<dim3(NC, HEADS), dim3(256), 0, stream>>>(qk_part, v_b, gamma, beta, KV, Z, y_b);

    gemm_wo<<<64, dim3(512), 0, stream>>>(y_b, wo_b, out);
}

// Round 18
// 80.292 us; speedup vs baseline: 1.2763x; 1.0256x over previous
//
#include <hip/hip_runtime.h>
#include <hip/hip_bf16.h>

#define HID 1024
#define HEADS 16
#define FEAT 16
#define HD 64
#define T_LEN 1024
#define NFEAT 136   // 16 diag + 120 off-diag
#define CL 32       // chunk length
#define NC 32       // chunks per head
#define SSTATE (NFEAT * HD)  // 8704

typedef __attribute__((ext_vector_type(8))) short short8;
typedef __attribute__((ext_vector_type(4))) float f32x4;

// upper-triangle index pair tables (i<j of 16)
__device__ const unsigned char IU_d[120] = {
    0,0,0,0,0,0,0,0,0,0,0,0,0,0,0,
    1,1,1,1,1,1,1,1,1,1,1,1,1,1,
    2,2,2,2,2,2,2,2,2,2,2,2,2,
    3,3,3,3,3,3,3,3,3,3,3,3,
    4,4,4,4,4,4,4,4,4,4,4,
    5,5,5,5,5,5,5,5,5,5,
    6,6,6,6,6,6,6,6,6,
    7,7,7,7,7,7,7,7,
    8,8,8,8,8,8,8,
    9,9,9,9,9,9,
    10,10,10,10,10,
    11,11,11,11,
    12,12,12,
    13,13,
    14};
__device__ const unsigned char JU_d[120] = {
    1,2,3,4,5,6,7,8,9,10,11,12,13,14,15,
    2,3,4,5,6,7,8,9,10,11,12,13,14,15,
    3,4,5,6,7,8,9,10,11,12,13,14,15,
    4,5,6,7,8,9,10,11,12,13,14,15,
    5,6,7,8,9,10,11,12,13,14,15,
    6,7,8,9,10,11,12,13,14,15,
    7,8,9,10,11,12,13,14,15,
    8,9,10,11,12,13,14,15,
    9,10,11,12,13,14,15,
    10,11,12,13,14,15,
    11,12,13,14,15,
    12,13,14,15,
    13,14,15,
    14,15,
    15};

// ---------------------------------------------------------------------------
// f32 <-> bf16 helpers
// ---------------------------------------------------------------------------
__device__ __forceinline__ unsigned short f2bf(float f) {
    union { float f; unsigned int u; } x;
    x.f = f;
    unsigned int u = x.u;
    unsigned int r = u + 0x7fffu + ((u >> 16) & 1u);
    return (unsigned short)(r >> 16);
}
__device__ __forceinline__ float bf2f(unsigned short s) {
    union { unsigned int u; float f; } x;
    x.u = ((unsigned int)s) << 16;
    return x.f;
}

// T2 swizzle: within each 64-col K-tile, 16B block b (0..7) of row r is
// STORED at block b ^ (r&7).
__device__ __forceinline__ int swz_col(int row, int k) {
    return (k & ~63) | ((((k >> 3) & 7) ^ (row & 7)) << 3);
}

// ---------------------------------------------------------------------------
// Fused conversion kernel (R15 verbatim).
// ---------------------------------------------------------------------------
__device__ __forceinline__ void split_store2(const float* __restrict__ in,
                                             unsigned short* __restrict__ out,
                                             int i, int rowoff) {
    float4 a = *(const float4*)&in[i];
    float4 b = *(const float4*)&in[i + 4];
    float x[8] = {a.x, a.y, a.z, a.w, b.x, b.y, b.z, b.w};
    union { unsigned short s[8]; short8 v; } hi, lo;
#pragma unroll
    for (int j = 0; j < 8; ++j) {
        hi.s[j] = f2bf(x[j]);
        lo.s[j] = f2bf(x[j] - bf2f(hi.s[j]));
    }
    int row = (i >> 10) + rowoff;
    int ks = swz_col(row, i & 1023);
    unsigned short* base = out + (size_t)row * 2048 + ks;
    *(short8*)&base[0]    = hi.v;
    *(short8*)&base[1024] = lo.v;
}

__device__ __forceinline__ void plain_store(const float* __restrict__ in,
                                            unsigned short* __restrict__ out, int i) {
    float4 a = *(const float4*)&in[i];
    float4 b = *(const float4*)&in[i + 4];
    union { unsigned short s[8]; short8 v; } o;
    o.s[0] = f2bf(a.x); o.s[1] = f2bf(a.y); o.s[2] = f2bf(a.z); o.s[3] = f2bf(a.w);
    o.s[4] = f2bf(b.x); o.s[5] = f2bf(b.y); o.s[6] = f2bf(b.z); o.s[7] = f2bf(b.w);
    int row = i >> 10;
    int ks = swz_col(row, i & 1023);
    *(short8*)&out[(size_t)row * 1024 + ks] = o.v;
}

__global__ __launch_bounds__(256) void cvt_all(const float* __restrict__ hs,
                                               const float* __restrict__ Wq,
                                               const float* __restrict__ Wk,
                                               const float* __restrict__ Wv,
                                               const float* __restrict__ Wo,
                                               unsigned short* __restrict__ hs2,
                                               unsigned short* __restrict__ wqk2,
                                               unsigned short* __restrict__ wv_b,
                                               unsigned short* __restrict__ wo_b) {
    int bx = blockIdx.x;
    int tid = threadIdx.x;
    if (bx < 512) {
        split_store2(hs, hs2, (bx * 256 + tid) * 8, 0);
    } else if (bx < 640) {
        split_store2(Wq, wqk2, ((bx - 512) * 256 + tid) * 8, 0);
    } else if (bx < 768) {
        split_store2(Wk, wqk2, ((bx - 640) * 256 + tid) * 8, 256);
    } else if (bx < 1280) {
        plain_store(Wv, wv_b, ((bx - 768) * 256 + tid) * 8);
    } else {
        plain_store(Wo, wo_b, ((bx - 1280) * 256 + tid) * 8);
    }
}

// ---------------------------------------------------------------------------
// async global->LDS copy
// ---------------------------------------------------------------------------
__device__ __forceinline__ void async_copy16(const void* g, const void* l) {
    __builtin_amdgcn_global_load_lds(
        (const __attribute__((address_space(1))) void*)(uintptr_t)g,
        (__attribute__((address_space(3))) void*)(uintptr_t)l, 16, 0, 0);
}

#define BAR_ONLY()   asm volatile("s_barrier" ::: "memory")
#define SYNC_KEEP(N) asm volatile("s_waitcnt vmcnt(" #N ")\n\ts_barrier" ::: "memory")

// ---------------------------------------------------------------------------
// BK=64, lookahead-3, 4-buffer pipelined 512-thread (8-wave) bf16 MFMA GEMM
// (R15 verbatim).
// ---------------------------------------------------------------------------
__device__ __forceinline__ void gemm_pipe512(const unsigned short* __restrict__ A,
                                             const unsigned short* __restrict__ B,
                                             void* __restrict__ Cv,
                                             int lda, int ldb, int ldc,
                                             int bm, int bn, int ntiles, int out_bf16,
                                             unsigned short (&As)[4][8192],
                                             unsigned short (&Bs)[4][8192]) {
    const int tid = threadIdx.x;
    const int wave = tid >> 6;
    const int lane = tid & 63;
    const int wr = wave >> 1;
    const int wc = wave & 1;
    const int fr = lane & 15;
    const int fq = lane >> 4;
    const int srow = tid >> 3;
    const int scol = (tid & 7) << 3;

    f32x4 acc[2][4];
#pragma unroll
    for (int i = 0; i < 2; ++i)
#pragma unroll
        for (int j = 0; j < 4; ++j) acc[i][j] = (f32x4)0.f;

    auto stage = [&](int buf, int tile) {
        const int k0 = tile << 6;
        async_copy16(&A[(size_t)(bm + srow) * lda + k0 + scol],
                     &As[buf][wave * 512]);
        async_copy16(&A[(size_t)(bm + 64 + srow) * lda + k0 + scol],
                     &As[buf][4096 + wave * 512]);
        async_copy16(&B[(size_t)(bn + srow) * ldb + k0 + scol],
                     &Bs[buf][wave * 512]);
        async_copy16(&B[(size_t)(bn + 64 + srow) * ldb + k0 + scol],
                     &Bs[buf][4096 + wave * 512]);
    };
    auto compute = [&](int buf) {
        short8 a[2][2], b[4][2];
#pragma unroll
        for (int i = 0; i < 2; ++i)
#pragma unroll
            for (int kh = 0; kh < 2; ++kh) {
                int r = wr * 32 + i * 16 + fr;
                int blk = (kh * 4 + fq) ^ (r & 7);
                a[i][kh] = *(const short8*)&As[buf][r * 64 + (blk << 3)];
            }
#pragma unroll
        for (int j = 0; j < 4; ++j)
#pragma unroll
            for (int kh = 0; kh < 2; ++kh) {
                int r = wc * 64 + j * 16 + fr;
                int blk = (kh * 4 + fq) ^ (r & 7);
                b[j][kh] = *(const short8*)&Bs[buf][r * 64 + (blk << 3)];
            }
#pragma unroll
        for (int i = 0; i < 2; ++i)
#pragma unroll
            for (int j = 0; j < 4; ++j) {
                acc[i][j] = __builtin_amdgcn_mfma_f32_16x16x32_bf16(a[i][0], b[j][0], acc[i][j], 0, 0, 0);
                acc[i][j] = __builtin_amdgcn_mfma_f32_16x16x32_bf16(a[i][1], b[j][1], acc[i][j], 0, 0, 0);
            }
    };

    stage(0, 0);
    stage(1, 1);
    stage(2, 2);
    for (int it = 0; it < ntiles - 3; ++it) {
        BAR_ONLY();
        stage((it + 3) & 3, it + 3);
        SYNC_KEEP(12);
        compute(it & 3);
    }
    SYNC_KEEP(8);
    compute((ntiles - 3) & 3);
    SYNC_KEEP(4);
    compute((ntiles - 2) & 3);
    SYNC_KEEP(0);
    compute((ntiles - 1) & 3);

#pragma unroll
    for (int i = 0; i < 2; ++i)
#pragma unroll
        for (int j = 0; j < 4; ++j) {
            int col = bn + wc * 64 + j * 16 + fr;
#pragma unroll
            for (int r = 0; r < 4; ++r) {
                int row = bm + wr * 32 + i * 16 + fq * 4 + r;
                if (out_bf16)
                    ((unsigned short*)Cv)[(size_t)row * ldc + col] = f2bf(acc[i][j][r]);
                else
                    ((float*)Cv)[(size_t)row * ldc + col] = acc[i][j][r];
            }
        }
}

// ---------------------------------------------------------------------------
// Grouped QKV GEMM, 160 blocks x 16 K-iters (R15 verbatim).
// ---------------------------------------------------------------------------
__global__ __launch_bounds__(512) void gemm_qkv(const unsigned short* __restrict__ hs2,
                                                const unsigned short* __restrict__ wqk2,
                                                const unsigned short* __restrict__ wv_b,
                                                float* __restrict__ qk_part,
                                                unsigned short* __restrict__ v_b) {
    __shared__ __align__(16) unsigned short As[4][8192];
    __shared__ __align__(16) unsigned short Bs[4][8192];
    const int bx = blockIdx.x;
    if (bx < 96) {
        int seg = bx >> 5, r = bx & 31;
        int bm = (r >> 2) * 128, bn = (r & 3) * 128;
        const unsigned short* A = hs2 + (seg == 1 ? 1024 : 0);
        const unsigned short* B = wqk2 + (seg == 2 ? 1024 : 0);
        gemm_pipe512(A, B, qk_part + (size_t)seg * (1024 * 512),
                     2048, 2048, 512, bm, bn, 16, 0, As, Bs);
    } else {
        int r = bx - 96;
        int bm = (r >> 3) * 128, bn = (r & 7) * 128;
        gemm_pipe512(hs2, wv_b, v_b, 2048, 1024, 1024, bm, bn, 16, 1, As, Bs);
    }
}

// ---------------------------------------------------------------------------
// Wo GEMM (R15 verbatim).
// ---------------------------------------------------------------------------
__global__ __launch_bounds__(512) void gemm_wo(const unsigned short* __restrict__ y_b,
                                               const unsigned short* __restrict__ wo_b,
                                               float* __restrict__ out) {
    __shared__ __align__(16) unsigned short As[4][8192];
    __shared__ __align__(16) unsigned short Bs[4][8192];
    const int r = blockIdx.x;
    const int bm = (r >> 3) * 128, bn = (r & 7) * 128;
    gemm_pipe512(y_b, wo_b, out, 1024, 1024, 1024, bm, bn, 16, 0, As, Bs);
}

// ---------------------------------------------------------------------------
// Parallel LN: 4 threads per row (p = tid&3, quad-aligned in the wave).
// Each thread: 3 float4 loads (its 4 features x 3 split partials),
// 4-lane shfl_xor reduce for mu/var, writes its 4 xn values to LDS.
// ---------------------------------------------------------------------------
__device__ __forceinline__ void ln_row_par4(const float* __restrict__ qk_part,
                                            int col0, int h, int t,
                                            const float* __restrict__ gamma,
                                            const float* __restrict__ beta,
                                            float* __restrict__ xn_row, int p) {
    const float* base = qk_part + (size_t)t * 512 + col0 + h * FEAT + p * 4;
    float4 x0 = *(const float4*)&base[0];
    float4 x1 = *(const float4*)&base[524288];
    float4 x2 = *(const float4*)&base[1048576];
    float x[4] = {x0.x + x1.x + x2.x, x0.y + x1.y + x2.y,
                  x0.z + x1.z + x2.z, x0.w + x1.w + x2.w};
    float s = (x[0] + x[1]) + (x[2] + x[3]);
    s += __shfl_xor(s, 1);
    s += __shfl_xor(s, 2);
    float mu = s * (1.f / 16.f);
    float vs = 0.f;
#pragma unroll
    for (int j = 0; j < 4; ++j) {
        float dd = x[j] - mu;
        vs += dd * dd;
    }
    vs += __shfl_xor(vs, 1);
    vs += __shfl_xor(vs, 2);
    float rstd = rsqrtf(vs * (1.f / 16.f) + 1e-5f);
    float4 g = *(const float4*)&gamma[p * 4];
    float4 bb = *(const float4*)&beta[p * 4];
    float gv[4] = {g.x, g.y, g.z, g.w};
    float bv[4] = {bb.x, bb.y, bb.z, bb.w};
#pragma unroll
    for (int j = 0; j < 4; ++j)
        xn_row[p * 4 + j] = (x[j] - mu) * rstd * gv[j] + bv[j];
}

// ---------------------------------------------------------------------------
// Phase 1: per-chunk KV sums + Z sums; LN parallelized (128 threads, 4/row).
// ---------------------------------------------------------------------------
__global__ __launch_bounds__(256) void chunk_kv(const float* __restrict__ qk_part,
                                                const unsigned short* __restrict__ v_b,
                                                const float* __restrict__ gamma,
                                                const float* __restrict__ beta,
                                                float* __restrict__ KV,
                                                float* __restrict__ Z) {
    const int c = blockIdx.x;
    const int h = blockIdx.y;
    const int tid = threadIdx.x;
    __shared__ float xn_s[CL][17];
    __shared__ float pk_s[CL * NFEAT];
    __shared__ unsigned char iu_s[120], ju_s[120];

    const int d = tid & 63;
    const int fg = tid >> 6;

    if (tid < 120) { iu_s[tid] = IU_d[tid]; ju_s[tid] = JU_d[tid]; }

    float v[CL];
#pragma unroll
    for (int t = 0; t < CL; ++t)
        v[t] = bf2f(v_b[(size_t)(c * CL + t) * 1024 + h * HD + d]);

    if (tid < 128)
        ln_row_par4(qk_part, 256, h, c * CL + (tid >> 2), gamma, beta,
                    xn_s[tid >> 2], tid & 3);
    __syncthreads();

    {
        int r = tid >> 3, p = tid & 7;
        const float c1 = 0.25f;
        const float c2 = 0.35355339059327373f;
#pragma unroll
        for (int n = 0; n < 17; ++n) {
            int idx = p * 17 + n;
            float val;
            if (idx < 16) {
                float a = xn_s[r][idx];
                val = a * a * c1;
            } else {
                val = xn_s[r][iu_s[idx - 16]] * xn_s[r][ju_s[idx - 16]] * c2;
            }
            pk_s[r * NFEAT + idx] = val;
        }
    }
    __syncthreads();

    float* kv_out = KV + ((size_t)(h * NC + c)) * SSTATE;
    float* z_out = Z + ((size_t)(h * NC + c)) * NFEAT;
#pragma unroll
    for (int np = 0; np < 17; ++np) {
        int f = fg * 34 + 2 * np;
        float acc0 = 0.f, acc1 = 0.f, z0 = 0.f, z1 = 0.f;
#pragma unroll
        for (int t = 0; t < CL; ++t) {
            float2 pk = *(const float2*)&pk_s[t * NFEAT + f];
            acc0 += pk.x * v[t];
            acc1 += pk.y * v[t];
            z0 += pk.x;
            z1 += pk.y;
        }
        kv_out[(f + 0) * HD + d] = acc0;
        kv_out[(f + 1) * HD + d] = acc1;
        if (d == 0) { z_out[f] = z0; z_out[f + 1] = z1; }
    }
}

// ---------------------------------------------------------------------------
// Phase 2: exclusive prefix scan over chunks (R15 verbatim).
// ---------------------------------------------------------------------------
__global__ __launch_bounds__(256) void chunk_scan(float* __restrict__ KV,
                                                  float* __restrict__ Z) {
    const int bx = blockIdx.x;
    const int h = blockIdx.y;
    const int tid = threadIdx.x;
    if (bx < 34) {
        float* base = KV + (size_t)h * NC * SSTATE + bx * 256 + tid;
        float val[NC];
#pragma unroll
        for (int c = 0; c < NC; ++c) val[c] = base[(size_t)c * SSTATE];
        float run = 0.f;
#pragma unroll
        for (int c = 0; c < NC; ++c) {
            float t = val[c];
            val[c] = run;
            run += t;
        }
#pragma unroll
        for (int c = 0; c < NC; ++c) base[(size_t)c * SSTATE] = val[c];
    } else if (tid < NFEAT) {
        float* base = Z + (size_t)h * NC * NFEAT + tid;
        float val[NC];
#pragma unroll
        for (int c = 0; c < NC; ++c) val[c] = base[(size_t)c * NFEAT];
        float run = 0.f;
#pragma unroll
        for (int c = 0; c < NC; ++c) {
            float t = val[c];
            val[c] = run;
            run += t;
        }
#pragma unroll
        for (int c = 0; c < NC; ++c) base[(size_t)c * NFEAT] = val[c];
    }
}

// ---------------------------------------------------------------------------
// Phase 3: per-chunk output; LN parallelized (256 threads, 4/row over q+k).
// ---------------------------------------------------------------------------
__global__ __launch_bounds__(256) void chunk_out(const float* __restrict__ qk_part,
                                                 const unsigned short* __restrict__ v_b,
                                                 const float* __restrict__ gamma,
                                                 const float* __restrict__ beta,
                                                 const float* __restrict__ KV,
                                                 const float* __restrict__ Z,
                                                 unsigned short* __restrict__ y_b) {
    const int c = blockIdx.x;
    const int h = blockIdx.y;
    const int tid = threadIdx.x;

    __shared__ float xnq_s[CL][17];
    __shared__ float xnk_s[CL][17];
    __shared__ float pq_s[CL * 137];
    __shared__ float pk_s[CL * 137];
    __shared__ float A_s[CL * CL];
    __shared__ unsigned char iu_s[120], ju_s[120];

    const int d = tid & 63;
    const int tg = tid >> 6;

    if (tid < 120) { iu_s[tid] = IU_d[tid]; ju_s[tid] = JU_d[tid]; }

    float v[CL];
#pragma unroll
    for (int t = 0; t < CL; ++t)
        v[t] = bf2f(v_b[(size_t)(c * CL + t) * 1024 + h * HD + d]);

    // parallel LN: threads 0..127 -> q rows, 128..255 -> k rows; 4 threads/row
    {
        int mat = tid >> 7;
        int r = (tid & 127) >> 2;
        int p = tid & 3;
        ln_row_par4(qk_part, mat ? 256 : 0, h, c * CL + r, gamma, beta,
                    (mat ? xnk_s : xnq_s)[r], p);
    }
    for (int e = tid; e < CL * CL; e += 256) A_s[e] = 0.f;
    __syncthreads();

    {
        int mat = tid >> 7;
        int r = (tid & 127) >> 2;
        int p = tid & 3;
        const float (*xn)[17] = mat ? xnk_s : xnq_s;
        float* dst = (mat ? pk_s : pq_s) + (size_t)r * 137;
        const float c1 = 0.25f;
        const float c2 = 0.35355339059327373f;
#pragma unroll
        for (int n = 0; n < 34; ++n) {
            int idx = p * 34 + n;
            float val;
            if (idx < 16) {
                float a = xn[r][idx];
                val = a * a * c1;
            } else {
                val = xn[r][iu_s[idx - 16]] * xn[r][ju_s[idx - 16]] * c2;
            }
            dst[idx] = val;
        }
    }
    __syncthreads();

    for (int e = tid; e < 528; e += 256) {
        int t = (int)((sqrtf(8.f * e + 1.f) - 1.f) * 0.5f);
        int s = e - ((t * (t + 1)) >> 1);
        float acc = 0.f;
#pragma unroll 8
        for (int f = 0; f < NFEAT; ++f)
            acc += pq_s[t * 137 + f] * pk_s[s * 137 + f];
        A_s[t * CL + s] = acc;
    }
    __syncthreads();

    const float* kv_pref = KV + ((size_t)(h * NC + c)) * SSTATE;
    const float* z_pref = Z + ((size_t)(h * NC + c)) * NFEAT;

    float num[8], den[8];
#pragma unroll
    for (int i = 0; i < 8; ++i) { num[i] = 0.f; den[i] = 0.f; }

#pragma unroll 8
    for (int f = 0; f < NFEAT; ++f) {
        float sp = kv_pref[f * HD + d];
        float zp = z_pref[f];
#pragma unroll
        for (int i = 0; i < 8; ++i) {
            float pq = pq_s[(tg * 8 + i) * 137 + f];
            num[i] += pq * sp;
            den[i] += pq * zp;
        }
    }
#pragma unroll
    for (int s = 0; s < CL; ++s) {
        float vv = v[s];
#pragma unroll
        for (int i = 0; i < 8; ++i) {
            float a = A_s[(tg * 8 + i) * CL + s];
            num[i] += a * vv;
            den[i] += a;
        }
    }
#pragma unroll
    for (int i = 0; i < 8; ++i) {
        int t = c * CL + tg * 8 + i;
        int ds = ((((d >> 3) ^ (t & 7))) << 3) | (d & 7);
        y_b[(size_t)t * 1024 + h * HD + ds] = f2bf(num[i] / (den[i] + 1e-5f));
    }
}

extern "C" void kernel_launch(void* const* d_in, const int* in_sizes, int n_in,
                              void* d_out, int out_size, void* d_ws, size_t ws_size,
                              hipStream_t stream) {
    const float* hs    = (const float*)d_in[0];
    const float* Wq    = (const float*)d_in[1];
    const float* Wk    = (const float*)d_in[2];
    const float* Wv    = (const float*)d_in[3];
    const float* Wo    = (const float*)d_in[4];
    const float* gamma = (const float*)d_in[5];
    const float* beta  = (const float*)d_in[6];
    float* out = (float*)d_out;

    float* ws = (float*)d_ws;
    float* qk_part = ws;                                   // 3*1024*512
    float* KV      = qk_part + 3 * 1024 * 512;             // 16*32*8704
    float* Z       = KV + (size_t)HEADS * NC * SSTATE;     // 16*32*136
    unsigned short* hs2  = (unsigned short*)(Z + HEADS * NC * NFEAT);  // 1024*2048
    unsigned short* wqk2 = hs2 + (size_t)1024 * 2048;      // 512*2048
    unsigned short* wv_b = wqk2 + (size_t)512 * 2048;      // 1024*1024
    unsigned short* wo_b = wv_b + (size_t)1024 * 1024;     // 1024*1024
    unsigned short* v_b  = wo_b + (size_t)1024 * 1024;     // 1024*1024
    unsigned short* y_b  = v_b + (size_t)1024 * 1024;      // 1024*1024

    cvt_all<<<1792, dim3(256), 0, stream>>>(hs, Wq, Wk, Wv, Wo, hs2, wqk2, wv_b, wo_b);

    gemm_qkv<<<160, dim3(512), 0, stream>>>(hs2, wqk2, wv_b, qk_part, v_b);

    chunk_kv<<<dim3(NC, HEADS), dim3(256), 0, stream>>>(qk_part, v_b, gamma, beta, KV, Z);
    chunk_scan<<<dim3(35, HEADS), dim3(256), 0, stream>>>(KV, Z);
    chunk_out<<<dim3(NC, HEADS), dim3(256), 0, stream>>>(qk_part, v_b, gamma, beta, KV, Z, y_b);

    gemm_wo<<<64, dim3(512), 0, stream>>>(y_b, wo_b, out);
}